// Round 2
// 607.071 us; speedup vs baseline: 1.0284x; 1.0284x over previous
//
#include <hip/hip_runtime.h>
#include <hip/hip_bf16.h>

#define NTOK 49
#define DIM 192
#define NHEAD 6
#define HD 32
#define SCALE_F 0.1767766952966369f  // 32^-0.5

typedef __attribute__((ext_vector_type(8))) short bf16x8;
typedef __attribute__((ext_vector_type(4))) float f32x4;
typedef __attribute__((ext_vector_type(4))) unsigned int u32x4;

__device__ __forceinline__ unsigned short f2bf(float f) {
    unsigned int u = __float_as_uint(f);
    unsigned int r = (u + 0x7FFF + ((u >> 16) & 1)) >> 16;  // RNE (finite inputs)
    return (unsigned short)r;
}
__device__ __forceinline__ float bf2f(unsigned short h) {
    return __uint_as_float(((unsigned int)h) << 16);
}
// pack 2 f32 -> u32 of 2 bf16 (lo -> bits 15:0), RNE
__device__ __forceinline__ unsigned int cvtpk(float lo, float hi) {
    unsigned int r;
    asm("v_cvt_pk_bf16_f32 %0, %1, %2" : "=v"(r) : "v"(lo), "v"(hi));
    return r;
}

// ---- LDS: only the x / O staging tile (everything else lives in registers) ----
#define SX_STRIDE 200                 // 400B rows -> 2-way bank alias (free)
#define SX_ELEMS (64 * 200)
#define SMEM_BYTES (SX_ELEMS * 2)     // 25600 B -> LDS no longer caps occupancy

// ---- workspace layout (bytes) ----
#define WS_FLAG_OFF 0
#define WS_WTQKV_OFF 16
#define WS_WTPROJ_OFF (WS_WTQKV_OFF + 576 * 192 * 2)   // 221200
#define WS_QKVB_OFF (WS_WTPROJ_OFF + 192 * 192 * 2)    // 294928
#define WS_PROJB_OFF (WS_QKVB_OFF + 576 * 4)           // 297232
#define WS_BIAS_OFF (WS_PROJB_OFF + 192 * 4)           // 298000 (16B aligned)
#define WS_BYTES (WS_BIAS_OFF + NHEAD * 64 * 64 * 4)   // 396304

// Detect whether float inputs are fp32 (flag=1) or bf16 (flag=0).
__global__ void detect_dtype(const unsigned short* __restrict__ xraw, int* __restrict__ flag) {
    if (threadIdx.x == 0 && blockIdx.x == 0) {
        int bad = 0;
        for (int i = 0; i < 128; ++i) {
            float v = bf2f(xraw[i]);
            if (!(fabsf(v) < 1000.0f)) bad = 1;  // catches NaN too
        }
        *flag = bad;
    }
}

__device__ __forceinline__ float rd_any(const void* p, int i, int is_fp32) {
    return is_fp32 ? ((const float*)p)[i] : bf2f(((const unsigned short*)p)[i]);
}

// Normalize params into ws: transposed bf16 weights, fp32 biases, and the
// relative-position bias pre-gathered into the exact S^T fragment layout:
// biasST[h][lane][jt][mt][r] = bias[h][rel[m][j]] with j=jt*16+(lane>>4)*4+r,
// m=mt*16+(lane&15); j>=49 slots hold -1e9 (mask folded into the table).
__global__ void prep_params(const void* __restrict__ qkv_w, const void* __restrict__ proj_w,
                            const void* __restrict__ qkv_b, const void* __restrict__ proj_b,
                            const void* __restrict__ bias_table, const int* __restrict__ rel_idx,
                            char* __restrict__ ws) {
    const int is_fp32 = *(const int*)(ws + WS_FLAG_OFF);
    unsigned short* WtQkv = (unsigned short*)(ws + WS_WTQKV_OFF);
    unsigned short* WtProj = (unsigned short*)(ws + WS_WTPROJ_OFF);
    float* fQkvB = (float*)(ws + WS_QKVB_OFF);
    float* fProjB = (float*)(ws + WS_PROJB_OFF);
    float* fBiasST = (float*)(ws + WS_BIAS_OFF);

    int t = blockIdx.x * blockDim.x + threadIdx.x;
    if (t < 110592) {                       // WtQkv[n][k] = qkv_w[k][n]
        int n = t / 192, k = t - n * 192;
        WtQkv[t] = f2bf(rd_any(qkv_w, k * 576 + n, is_fp32));
        return;
    }
    int t2 = t - 110592;
    if (t2 < 36864) {                       // WtProj[n][k] = proj_w[k][n]
        int n = t2 / 192, k = t2 - n * 192;
        WtProj[t2] = f2bf(rd_any(proj_w, k * 192 + n, is_fp32));
        return;
    }
    int t3 = t2 - 36864;
    if (t3 < 576) { fQkvB[t3] = rd_any(qkv_b, t3, is_fp32); return; }
    int t4 = t3 - 576;
    if (t4 < 192) { fProjB[t4] = rd_any(proj_b, t4, is_fp32); return; }
    int t5 = t4 - 192;
    if (t5 < NHEAD * 64 * 64) {
        int h = t5 >> 12;
        int rem = t5 & 4095;
        int lane = rem >> 6;
        int idx = rem & 63;                 // jt*16 + mt*4 + r
        int jt = idx >> 4, mt = (idx >> 2) & 3, r = idx & 3;
        int j = jt * 16 + (lane >> 4) * 4 + r;
        int m = mt * 16 + (lane & 15);
        float val;
        if (j >= NTOK) val = -1e9f;         // masked key column
        else if (m >= NTOK) val = 0.0f;     // padded query row (never stored)
        else val = rd_any(bias_table, rel_idx[m * NTOK + j] * NHEAD + h, is_fp32);
        fBiasST[t5] = val;
    }
}

// Build an A/B fragment (row=l15, k=quad*8..+7) from D-layout packed bf16 pairs.
// a0,a1 = pk words (r01, r23) of the ct=0 source tile; b0,b1 = ct=1 tile.
// The ct-select MUST happen at the destination: __shfl evaluates its value
// argument in the SOURCE lane's context, and each source word pair is read by
// two destination quads wanting different ct. So shuffle both, select by the
// destination's hi2.
__device__ __forceinline__ bf16x8 bld_frag(int a0, int a1, int b0, int b1,
                                           int Llo, int Lhi, bool hi2) {
    int a0l = __shfl(a0, Llo, 64), b0l = __shfl(b0, Llo, 64);
    int a1l = __shfl(a1, Llo, 64), b1l = __shfl(b1, Llo, 64);
    int a0h = __shfl(a0, Lhi, 64), b0h = __shfl(b0, Lhi, 64);
    int a1h = __shfl(a1, Lhi, 64), b1h = __shfl(b1, Lhi, 64);
    u32x4 u;
    u[0] = (unsigned int)(hi2 ? b0l : a0l);
    u[1] = (unsigned int)(hi2 ? b1l : a1l);
    u[2] = (unsigned int)(hi2 ? b0h : a0h);
    u[3] = (unsigned int)(hi2 ? b1h : a1h);
    return __builtin_bit_cast(bf16x8, u);
}

__global__ __launch_bounds__(384, 3)  // 3 waves/SIMD -> 2 blocks/CU (VGPR cap ~168)
void win_attn_fused(const void* __restrict__ X,
                    const char* __restrict__ ws,
                    void* __restrict__ Out) {
    extern __shared__ char smem[];
    unsigned short* sX = (unsigned short*)smem;

    const unsigned short* WtQkv = (const unsigned short*)(ws + WS_WTQKV_OFF);
    const unsigned short* WtProj = (const unsigned short*)(ws + WS_WTPROJ_OFF);
    const float* fQkvB = (const float*)(ws + WS_QKVB_OFF);
    const float* fProjB = (const float*)(ws + WS_PROJB_OFF);
    const int is_fp32 = *(const int*)(ws + WS_FLAG_OFF);

    const int tid = threadIdx.x;
    const int wv = tid >> 6;       // wave index == head
    const int lane = tid & 63;
    const int l15 = lane & 15;
    const int quad = lane >> 4;
    const int q8 = quad * 8;
    const int q4 = quad * 4;
    const int bw = blockIdx.x;
    const int Llo = ((quad & 1) << 5) + l15;  // src lane for frag elems 0..3
    const int Lhi = Llo + 16;                 // src lane for frag elems 4..7
    const bool hi2 = (quad & 2) != 0;         // which source c/j-tile this quad needs

    // ---------- Phase 0: stage x (-> bf16) ----------
    if (is_fp32) {
        const float* xw = (const float*)X + (size_t)bw * (NTOK * DIM);
        for (int t = tid; t < (NTOK * DIM) / 4; t += 384) {  // 2352 float4
            int e = t * 4;
            int row = e / DIM;
            int col = e - row * DIM;
            float4 v = *(const float4*)(xw + e);
            ushort4 o;
            o.x = f2bf(v.x); o.y = f2bf(v.y); o.z = f2bf(v.z); o.w = f2bf(v.w);
            *(ushort4*)(sX + row * SX_STRIDE + col) = o;
        }
    } else {
        const unsigned short* xw = (const unsigned short*)X + (size_t)bw * (NTOK * DIM);
        for (int t = tid; t < (NTOK * DIM) / 8; t += 384) {  // 1176 vec8
            int e = t * 8;
            int row = e / DIM;
            int col = e - row * DIM;
            *(bf16x8*)(sX + row * SX_STRIDE + col) = *(const bf16x8*)(xw + e);
        }
    }
    {
        bf16x8 z8 = {0, 0, 0, 0, 0, 0, 0, 0};
        for (int t = tid; t < 360; t += 384) {  // zero rows 49..63
            int e = t * 8;
            int row = 49 + e / DIM;
            int col = e % DIM;
            *(bf16x8*)(sX + row * SX_STRIDE + col) = z8;
        }
    }
    __syncthreads();

    // ---------- Phase 1: Q^T,K^T (swapped operands) and V = x@W + b ----------
    f32x4 accQT[2][4], accKT[2][4], accV[4][2];
    {
        f32x4 zf = {0.f, 0.f, 0.f, 0.f};
#pragma unroll
        for (int a = 0; a < 2; ++a)
#pragma unroll
            for (int b = 0; b < 4; ++b) { accQT[a][b] = zf; accKT[a][b] = zf; }
#pragma unroll
        for (int a = 0; a < 4; ++a)
#pragma unroll
            for (int b = 0; b < 2; ++b) accV[a][b] = zf;
    }
#pragma unroll
    for (int kb = 0; kb < 6; ++kb) {
        const int k0 = kb * 32 + q8;
        bf16x8 afr[4];
#pragma unroll
        for (int mt = 0; mt < 4; ++mt)
            afr[mt] = *(const bf16x8*)(sX + (mt * 16 + l15) * SX_STRIDE + k0);
#pragma unroll
        for (int ct = 0; ct < 2; ++ct) {
            const int n = wv * HD + ct * 16 + l15;
            bf16x8 wq = *(const bf16x8*)(WtQkv + (size_t)n * DIM + k0);
            bf16x8 wk = *(const bf16x8*)(WtQkv + (size_t)(n + DIM) * DIM + k0);
#pragma unroll
            for (int mt = 0; mt < 4; ++mt) {
                accQT[ct][mt] = __builtin_amdgcn_mfma_f32_16x16x32_bf16(wq, afr[mt], accQT[ct][mt], 0, 0, 0);
                accKT[ct][mt] = __builtin_amdgcn_mfma_f32_16x16x32_bf16(wk, afr[mt], accKT[ct][mt], 0, 0, 0);
            }
        }
#pragma unroll
        for (int nt = 0; nt < 2; ++nt) {
            const int n2 = wv * HD + nt * 16 + l15;
            bf16x8 wvv = *(const bf16x8*)(WtQkv + (size_t)(n2 + 2 * DIM) * DIM + k0);
#pragma unroll
            for (int mt = 0; mt < 4; ++mt)
                accV[mt][nt] = __builtin_amdgcn_mfma_f32_16x16x32_bf16(afr[mt], wvv, accV[mt][nt], 0, 0, 0);
        }
    }

    // epilogue: +bias (Q also *scale), pack reg-pairs to bf16x2 words
    int pkQ[2][4][2], pkK[2][4][2], pkV[4][2][2];
#pragma unroll
    for (int ct = 0; ct < 2; ++ct) {
        const float4 qb = *(const float4*)(fQkvB + wv * HD + ct * 16 + q4);
        const float4 kb4 = *(const float4*)(fQkvB + DIM + wv * HD + ct * 16 + q4);
#pragma unroll
        for (int mt = 0; mt < 4; ++mt) {
            pkQ[ct][mt][0] = cvtpk((accQT[ct][mt][0] + qb.x) * SCALE_F,
                                   (accQT[ct][mt][1] + qb.y) * SCALE_F);
            pkQ[ct][mt][1] = cvtpk((accQT[ct][mt][2] + qb.z) * SCALE_F,
                                   (accQT[ct][mt][3] + qb.w) * SCALE_F);
            pkK[ct][mt][0] = cvtpk(accKT[ct][mt][0] + kb4.x, accKT[ct][mt][1] + kb4.y);
            pkK[ct][mt][1] = cvtpk(accKT[ct][mt][2] + kb4.z, accKT[ct][mt][3] + kb4.w);
        }
    }
#pragma unroll
    for (int nt = 0; nt < 2; ++nt) {
        const float vb = fQkvB[2 * DIM + wv * HD + nt * 16 + l15];
#pragma unroll
        for (int mt = 0; mt < 4; ++mt) {
            pkV[mt][nt][0] = cvtpk(accV[mt][nt][0] + vb, accV[mt][nt][1] + vb);
            pkV[mt][nt][1] = cvtpk(accV[mt][nt][2] + vb, accV[mt][nt][3] + vb);
        }
    }

    // ---------- Phase 2: S^T = K Q^T (+bias), in-register softmax ----------
    bf16x8 qf[4], kf[4];
#pragma unroll
    for (int t = 0; t < 4; ++t) {
        qf[t] = bld_frag(pkQ[0][t][0], pkQ[0][t][1], pkQ[1][t][0], pkQ[1][t][1], Llo, Lhi, hi2);
        kf[t] = bld_frag(pkK[0][t][0], pkK[0][t][1], pkK[1][t][0], pkK[1][t][1], Llo, Lhi, hi2);
    }
    f32x4 accST[4][4];  // [jt][mt]: S^T[j=jt*16+q4+r][m=mt*16+l15]
    {
        f32x4 zf = {0.f, 0.f, 0.f, 0.f};
#pragma unroll
        for (int jt = 0; jt < 4; ++jt)
#pragma unroll
            for (int mt = 0; mt < 4; ++mt) accST[jt][mt] = zf;
    }
#pragma unroll
    for (int jt = 0; jt < 4; ++jt)
#pragma unroll
        for (int mt = 0; mt < 4; ++mt)
            accST[jt][mt] = __builtin_amdgcn_mfma_f32_16x16x32_bf16(kf[jt], qf[mt], accST[jt][mt], 0, 0, 0);

    // bias (mask folded in) — 16 coalesced f32x4 loads, L2-resident table
    {
        const f32x4* bST = (const f32x4*)(ws + WS_BIAS_OFF) + (size_t)(wv * 64 + lane) * 16;
#pragma unroll
        for (int jt = 0; jt < 4; ++jt)
#pragma unroll
            for (int mt = 0; mt < 4; ++mt)
                accST[jt][mt] += bST[jt * 4 + mt];
    }

    float inv[4];
#pragma unroll
    for (int mt = 0; mt < 4; ++mt) {
        float mx = accST[0][mt][0];
#pragma unroll
        for (int jt = 0; jt < 4; ++jt)
#pragma unroll
            for (int r = 0; r < 4; ++r) mx = fmaxf(mx, accST[jt][mt][r]);
        mx = fmaxf(mx, __shfl_xor(mx, 16, 64));
        mx = fmaxf(mx, __shfl_xor(mx, 32, 64));
        float s = 0.f;
#pragma unroll
        for (int jt = 0; jt < 4; ++jt)
#pragma unroll
            for (int r = 0; r < 4; ++r) {
                float e = __expf(accST[jt][mt][r] - mx);  // masked j -> exact 0
                accST[jt][mt][r] = e;
                s += e;
            }
        s += __shfl_xor(s, 16, 64);
        s += __shfl_xor(s, 32, 64);
        inv[mt] = 1.0f / s;
    }
    int pkP[4][4][2];
#pragma unroll
    for (int jt = 0; jt < 4; ++jt)
#pragma unroll
        for (int mt = 0; mt < 4; ++mt) {
            pkP[jt][mt][0] = cvtpk(accST[jt][mt][0] * inv[mt], accST[jt][mt][1] * inv[mt]);
            pkP[jt][mt][1] = cvtpk(accST[jt][mt][2] * inv[mt], accST[jt][mt][3] * inv[mt]);
        }

    // ---------- Phase 3: O = P V (all operands in registers) ----------
    bf16x8 vfr[2][2];
#pragma unroll
    for (int nt = 0; nt < 2; ++nt)
#pragma unroll
        for (int kb = 0; kb < 2; ++kb)
            vfr[nt][kb] = bld_frag(pkV[2 * kb][nt][0], pkV[2 * kb][nt][1],
                                   pkV[2 * kb + 1][nt][0], pkV[2 * kb + 1][nt][1], Llo, Lhi, hi2);
    f32x4 accO[4][2];
    {
        f32x4 zf = {0.f, 0.f, 0.f, 0.f};
#pragma unroll
        for (int mt = 0; mt < 4; ++mt)
#pragma unroll
            for (int nt = 0; nt < 2; ++nt) accO[mt][nt] = zf;
    }
#pragma unroll
    for (int kb = 0; kb < 2; ++kb)
#pragma unroll
        for (int mt = 0; mt < 4; ++mt) {
            bf16x8 ap = bld_frag(pkP[2 * kb][mt][0], pkP[2 * kb][mt][1],
                                 pkP[2 * kb + 1][mt][0], pkP[2 * kb + 1][mt][1], Llo, Lhi, hi2);
#pragma unroll
            for (int nt = 0; nt < 2; ++nt)
                accO[mt][nt] = __builtin_amdgcn_mfma_f32_16x16x32_bf16(ap, vfr[nt][kb], accO[mt][nt], 0, 0, 0);
        }

    __syncthreads();  // all waves done with phase-1 sX reads; sO overlays sX
    unsigned short* sO = sX;
#pragma unroll
    for (int nt = 0; nt < 2; ++nt)
#pragma unroll
        for (int mt = 0; mt < 4; ++mt)
#pragma unroll
            for (int r = 0; r < 4; ++r)
                sO[(mt * 16 + q4 + r) * SX_STRIDE + wv * HD + nt * 16 + l15] =
                    f2bf(accO[mt][nt][r]);
    __syncthreads();

    // ---------- Phase 4: out = O @ proj_w + proj_b ----------
    f32x4 accF[4][2];
    {
        f32x4 zf = {0.f, 0.f, 0.f, 0.f};
#pragma unroll
        for (int mt = 0; mt < 4; ++mt)
#pragma unroll
            for (int nt = 0; nt < 2; ++nt) accF[mt][nt] = zf;
    }
#pragma unroll
    for (int kb = 0; kb < 6; ++kb) {
        const int k0 = kb * 32 + q8;
        bf16x8 ao[4], bwf[2];
#pragma unroll
        for (int mt = 0; mt < 4; ++mt)
            ao[mt] = *(const bf16x8*)(sO + (mt * 16 + l15) * SX_STRIDE + k0);
#pragma unroll
        for (int nt = 0; nt < 2; ++nt) {
            const int n = wv * 32 + nt * 16 + l15;
            bwf[nt] = *(const bf16x8*)(WtProj + (size_t)n * DIM + k0);
        }
#pragma unroll
        for (int mt = 0; mt < 4; ++mt)
#pragma unroll
            for (int nt = 0; nt < 2; ++nt)
                accF[mt][nt] = __builtin_amdgcn_mfma_f32_16x16x32_bf16(ao[mt], bwf[nt], accF[mt][nt], 0, 0, 0);
    }
    if (is_fp32) {
        float* outw = (float*)Out + (size_t)bw * (NTOK * DIM);
#pragma unroll
        for (int nt = 0; nt < 2; ++nt) {
            const int c = wv * 32 + nt * 16 + l15;
            const float pb = fProjB[c];
#pragma unroll
            for (int mt = 0; mt < 4; ++mt)
#pragma unroll
                for (int r = 0; r < 4; ++r) {
                    const int m = mt * 16 + q4 + r;
                    if (m < NTOK) outw[m * DIM + c] = accF[mt][nt][r] + pb;
                }
        }
    } else {
        unsigned short* outw = (unsigned short*)Out + (size_t)bw * (NTOK * DIM);
#pragma unroll
        for (int nt = 0; nt < 2; ++nt) {
            const int c = wv * 32 + nt * 16 + l15;
            const float pb = fProjB[c];
#pragma unroll
            for (int mt = 0; mt < 4; ++mt)
#pragma unroll
                for (int r = 0; r < 4; ++r) {
                    const int m = mt * 16 + q4 + r;
                    if (m < NTOK) outw[m * DIM + c] = f2bf(accF[mt][nt][r] + pb);
                }
        }
    }
}

extern "C" void kernel_launch(void* const* d_in, const int* in_sizes, int n_in,
                              void* d_out, int out_size, void* d_ws, size_t ws_size,
                              hipStream_t stream) {
    const void* x = d_in[0];
    const void* qkv_w = d_in[1];
    const void* qkv_b = d_in[2];
    const void* proj_w = d_in[3];
    const void* proj_b = d_in[4];
    const void* bias_table = d_in[5];
    const int* rel_idx = (const int*)d_in[6];

    const int nwin = in_sizes[0] / (NTOK * DIM);  // 4096
    char* ws = (char*)d_ws;

    detect_dtype<<<1, 64, 0, stream>>>((const unsigned short*)x, (int*)(ws + WS_FLAG_OFF));
    {
        const int tot = 110592 + 36864 + 576 + 192 + NHEAD * 64 * 64;  // 172800
        prep_params<<<(tot + 255) / 256, 256, 0, stream>>>(qkv_w, proj_w, qkv_b, proj_b,
                                                           bias_table, rel_idx, ws);
    }
    win_attn_fused<<<nwin, 384, SMEM_BYTES, stream>>>(x, ws, d_out);
}